// Round 2
// baseline (493.561 us; speedup 1.0000x reference)
//
#include <hip/hip_runtime.h>
#include <stdint.h>

#define S_TOK 8192
#define MDIM  1024
#define HDIM  4096
#define ODIM  1024
#define NEXP  4
#define CAP   2048   // ceil(S/E)

typedef __attribute__((ext_vector_type(8))) short short8;
typedef __attribute__((ext_vector_type(4))) float floatx4;

__device__ __forceinline__ unsigned short f2bf(float x) {
  union { float f; unsigned u; } v; v.f = x;
  unsigned r = v.u + 0x7FFFu + ((v.u >> 16) & 1u);   // RNE
  return (unsigned short)(r >> 16);
}

__device__ __forceinline__ void gl_lds16(const void* g, void* l) {
  __builtin_amdgcn_global_load_lds(
      (const __attribute__((address_space(1))) void*)g,
      (__attribute__((address_space(3))) void*)l, 16, 0, 0);
}

__device__ __forceinline__ float gelu_tanh(float x) {
  // jax.nn.gelu approximate=True
  float z = 0.7978845608028654f * (x + 0.044715f * x * x * x);
  float t = 1.0f - 2.0f / (__expf(2.0f * z) + 1.0f);  // tanh, saturation-safe
  return 0.5f * x * (1.0f + t);
}

// ---------------- gate: logits (fp64 acc), softmax, argmax, gate sums ----------
__global__ __launch_bounds__(256) void gate_kernel(
    const float* __restrict__ feat, const float* __restrict__ gw,
    int* __restrict__ idx, float* __restrict__ gval, float* __restrict__ gsum)
{
  int wave = threadIdx.x >> 6, lane = threadIdx.x & 63;
  int s = blockIdx.x * 4 + wave;
  const float* f = feat + (size_t)s * MDIM;
  double a0 = 0, a1 = 0, a2 = 0, a3 = 0;
  #pragma unroll
  for (int j = 0; j < 16; ++j) {
    int m = lane + j * 64;
    float x = f[m];
    float4 w = ((const float4*)gw)[m];   // gate_w row m: 4 contiguous floats
    a0 += (double)x * w.x; a1 += (double)x * w.y;
    a2 += (double)x * w.z; a3 += (double)x * w.w;
  }
  #pragma unroll
  for (int off = 32; off; off >>= 1) {
    a0 += __shfl_down(a0, off); a1 += __shfl_down(a1, off);
    a2 += __shfl_down(a2, off); a3 += __shfl_down(a3, off);
  }
  __shared__ float bs[4];
  if (threadIdx.x < 4) bs[threadIdx.x] = 0.f;
  __syncthreads();
  if (lane == 0) {
    double lg[4] = {a0, a1, a2, a3};
    double mx = lg[0]; int bi = 0;
    #pragma unroll
    for (int e = 1; e < 4; ++e) if (lg[e] > mx) { mx = lg[e]; bi = e; }  // first-max
    float ex[4]; float den = 0.f;
    #pragma unroll
    for (int e = 0; e < 4; ++e) { ex[e] = __expf((float)(lg[e] - mx)); den += ex[e]; }
    float inv = 1.f / den;
    idx[s]  = bi;
    gval[s] = ex[bi] * inv;
    #pragma unroll
    for (int e = 0; e < 4; ++e) atomicAdd(&bs[e], ex[e] * inv);
  }
  __syncthreads();
  if (threadIdx.x < 4) atomicAdd(&gsum[threadIdx.x], bs[threadIdx.x]);
}

// ---------------- ordered per-expert rank scan (1 wave), l_aux -----------------
__global__ void scan_kernel(const int* __restrict__ idx, int* __restrict__ perm,
                            int* __restrict__ ne, const float* __restrict__ gsum,
                            float* __restrict__ laux)
{
  int lane = threadIdx.x;
  unsigned long long below = (lane == 0) ? 0ull : ((~0ull) >> (64 - lane));
  int off[4] = {0, 0, 0, 0};
  for (int base = 0; base < S_TOK; base += 512) {
    int v[8];
    #pragma unroll
    for (int j = 0; j < 8; ++j) v[j] = idx[base + j * 64 + lane];
    #pragma unroll
    for (int j = 0; j < 8; ++j) {
      int myE = v[j];
      int s = base + j * 64 + lane;
      #pragma unroll
      for (int e = 0; e < 4; ++e) {
        unsigned long long mb = __ballot(myE == e);
        if (myE == e) {
          int rank = off[e] + __popcll(mb & below);
          if (rank < CAP) perm[e * CAP + rank] = s;   // dropped tokens: no slot
        }
        off[e] += __popcll(mb);
      }
    }
  }
  if (lane < 4) ne[lane] = off[lane] < CAP ? off[lane] : CAP;
  if (lane == 0) {   // l_aux uses PRE-capacity counts and full softmax sums
    float l = 0.f;
    #pragma unroll
    for (int e = 0; e < 4; ++e)
      l += (gsum[e] * (1.0f / S_TOK)) * ((float)off[e] * (1.0f / S_TOK));
    *laux = l * (float)NEXP;
  }
}

// ---------------- cast + transpose weights: [R,C] f32 -> [C,R] bf16 ------------
__global__ __launch_bounds__(256) void transpose_cast(
    const float* __restrict__ in, unsigned short* __restrict__ out, int R, int Cc)
{
  __shared__ unsigned short tile[64][66];
  in  += (size_t)blockIdx.z * R * Cc;
  out += (size_t)blockIdx.z * R * Cc;
  int c0 = blockIdx.x * 64, r0 = blockIdx.y * 64;
  int tx = threadIdx.x & 15;
  int ty = threadIdx.x >> 4;
  #pragma unroll
  for (int p = 0; p < 4; ++p) {
    int r = ty + p * 16;
    float4 v = *(const float4*)(in + (size_t)(r0 + r) * Cc + c0 + tx * 4);
    tile[r][tx * 4 + 0] = f2bf(v.x);
    tile[r][tx * 4 + 1] = f2bf(v.y);
    tile[r][tx * 4 + 2] = f2bf(v.z);
    tile[r][tx * 4 + 3] = f2bf(v.w);
  }
  __syncthreads();
  #pragma unroll
  for (int p = 0; p < 4; ++p) {
    int c = ty + p * 16;
    ushort4 o;
    o.x = tile[tx * 4 + 0][c];
    o.y = tile[tx * 4 + 1][c];
    o.z = tile[tx * 4 + 2][c];
    o.w = tile[tx * 4 + 3][c];
    *(ushort4*)(out + (size_t)(c0 + c) * R + r0 + tx * 4) = o;
  }
}

// ---------------- gather kept tokens -> bf16 dispatch buffer -------------------
__global__ __launch_bounds__(256) void gather_kernel(
    const float* __restrict__ feat, const int* __restrict__ perm,
    const int* __restrict__ ne, unsigned short* __restrict__ disp)
{
  int b = blockIdx.x;
  int e = b >> 11, c = b & (CAP - 1);
  int m = threadIdx.x * 4;
  ushort4 o;
  if (c < ne[e]) {
    int s = perm[b];
    float4 v = *(const float4*)(feat + (size_t)s * MDIM + m);
    o.x = f2bf(v.x); o.y = f2bf(v.y); o.z = f2bf(v.z); o.w = f2bf(v.w);
  } else {
    o.x = o.y = o.z = o.w = 0;   // empty slot -> zero row (h row = gelu(0)=0)
  }
  *(ushort4*)(disp + (size_t)b * MDIM + m) = o;
}

// ---------------- fc1: disp[E*C,1024] @ w1t[E,4096,1024] -> gelu -> h bf16 -----
// Double-buffered LDS: stage(k+1) issued right after the barrier so its HBM
// latency is in flight during compute(k); next barrier's vmcnt(0) drain then
// costs only the residual.
__global__ __launch_bounds__(256) void fc1_kernel(
    const unsigned short* __restrict__ A, const unsigned short* __restrict__ Bt,
    const float* __restrict__ b1, unsigned short* __restrict__ Hb)
{
  const int e = blockIdx.z, nb = blockIdx.x, mb = blockIdx.y;
  const int tid = threadIdx.x, wave = tid >> 6, lane = tid & 63;

  __shared__ __align__(16) unsigned short smA[2][128 * 32];  // 2 x 8 KB
  __shared__ __align__(16) unsigned short smB[2][128 * 32];

  const char* Ag = (const char*)(A + ((size_t)e * CAP + (size_t)mb * 128) * MDIM);
  const char* Bg = (const char*)(Bt + ((size_t)e * HDIM + (size_t)nb * 128) * MDIM);

  int boff0 = (wave * 2 + 0) * 1024 + lane * 16;
  int boff1 = (wave * 2 + 1) * 1024 + lane * 16;
  const char* agp0 = Ag + (size_t)(boff0 >> 6) * 2048 + (boff0 & 63);
  const char* agp1 = Ag + (size_t)(boff1 >> 6) * 2048 + (boff1 & 63);
  const char* bgp0 = Bg + (size_t)(boff0 >> 6) * 2048 + (boff0 & 63);
  const char* bgp1 = Bg + (size_t)(boff1 >> 6) * 2048 + (boff1 & 63);
  const int so0 = (wave * 2 + 0) * 512;   // shorts
  const int so1 = (wave * 2 + 1) * 512;

  const int wm = (wave & 1) * 64, wn = (wave >> 1) * 64;
  const int fr = lane & 15, fq = lane >> 4;

  floatx4 acc[4][4] = {};

  // prologue: stage tile 0 into buf 0
  {
    gl_lds16(agp0, &smA[0][so0]);
    gl_lds16(agp1, &smA[0][so1]);
    gl_lds16(bgp0, &smB[0][so0]);
    gl_lds16(bgp1, &smB[0][so1]);
  }
  int cur = 0;
  for (int kt = 0; kt < MDIM / 32; ++kt) {
    __syncthreads();   // buf[cur] loads drained; prev reads of buf[cur^1] done
    if (kt + 1 < MDIM / 32) {
      int kb = (kt + 1) * 64;
      int nx = cur ^ 1;
      gl_lds16(agp0 + kb, &smA[nx][so0]);
      gl_lds16(agp1 + kb, &smA[nx][so1]);
      gl_lds16(bgp0 + kb, &smB[nx][so0]);
      gl_lds16(bgp1 + kb, &smB[nx][so1]);
    }
    short8 af[4], bfr[4];
    #pragma unroll
    for (int i = 0; i < 4; ++i)
      af[i] = *(const short8*)&smA[cur][(wm + i * 16 + fr) * 32 + fq * 8];
    #pragma unroll
    for (int j = 0; j < 4; ++j)
      bfr[j] = *(const short8*)&smB[cur][(wn + j * 16 + fr) * 32 + fq * 8];
    #pragma unroll
    for (int i = 0; i < 4; ++i)
      #pragma unroll
      for (int j = 0; j < 4; ++j)
        acc[i][j] = __builtin_amdgcn_mfma_f32_16x16x32_bf16(af[i], bfr[j], acc[i][j], 0, 0, 0);
    cur ^= 1;
  }

  unsigned short* Hrow = Hb + (size_t)e * CAP * HDIM;
  #pragma unroll
  for (int j = 0; j < 4; ++j) {
    int gn = nb * 128 + wn + j * 16 + fr;
    float bv = b1[e * HDIM + gn];
    #pragma unroll
    for (int i = 0; i < 4; ++i) {
      int m0 = mb * 128 + wm + i * 16 + fq * 4;
      #pragma unroll
      for (int r = 0; r < 4; ++r)
        Hrow[(size_t)(m0 + r) * HDIM + gn] = f2bf(gelu_tanh(acc[i][j][r] + bv));
    }
  }
}

// ---------------- fc2: h[E*C,4096] @ w2t[E,1024,4096] -> gated scatter ---------
__global__ __launch_bounds__(256) void fc2_kernel(
    const unsigned short* __restrict__ A, const unsigned short* __restrict__ Bt,
    const float* __restrict__ b2, const int* __restrict__ perm,
    const int* __restrict__ ne, const float* __restrict__ gval,
    float* __restrict__ out)
{
  const int e = blockIdx.z, nb = blockIdx.x, mb = blockIdx.y;
  const int tid = threadIdx.x, wave = tid >> 6, lane = tid & 63;

  __shared__ __align__(16) unsigned short smA[2][128 * 32];
  __shared__ __align__(16) unsigned short smB[2][128 * 32];

  const char* Ag = (const char*)(A + ((size_t)e * CAP + (size_t)mb * 128) * HDIM);
  const char* Bg = (const char*)(Bt + ((size_t)e * ODIM + (size_t)nb * 128) * HDIM);

  int boff0 = (wave * 2 + 0) * 1024 + lane * 16;
  int boff1 = (wave * 2 + 1) * 1024 + lane * 16;
  const char* agp0 = Ag + (size_t)(boff0 >> 6) * 8192 + (boff0 & 63);
  const char* agp1 = Ag + (size_t)(boff1 >> 6) * 8192 + (boff1 & 63);
  const char* bgp0 = Bg + (size_t)(boff0 >> 6) * 8192 + (boff0 & 63);
  const char* bgp1 = Bg + (size_t)(boff1 >> 6) * 8192 + (boff1 & 63);
  const int so0 = (wave * 2 + 0) * 512;
  const int so1 = (wave * 2 + 1) * 512;

  const int wm = (wave & 1) * 64, wn = (wave >> 1) * 64;
  const int fr = lane & 15, fq = lane >> 4;

  floatx4 acc[4][4] = {};

  {
    gl_lds16(agp0, &smA[0][so0]);
    gl_lds16(agp1, &smA[0][so1]);
    gl_lds16(bgp0, &smB[0][so0]);
    gl_lds16(bgp1, &smB[0][so1]);
  }
  int cur = 0;
  for (int kt = 0; kt < HDIM / 32; ++kt) {
    __syncthreads();
    if (kt + 1 < HDIM / 32) {
      int kb = (kt + 1) * 64;
      int nx = cur ^ 1;
      gl_lds16(agp0 + kb, &smA[nx][so0]);
      gl_lds16(agp1 + kb, &smA[nx][so1]);
      gl_lds16(bgp0 + kb, &smB[nx][so0]);
      gl_lds16(bgp1 + kb, &smB[nx][so1]);
    }
    short8 af[4], bfr[4];
    #pragma unroll
    for (int i = 0; i < 4; ++i)
      af[i] = *(const short8*)&smA[cur][(wm + i * 16 + fr) * 32 + fq * 8];
    #pragma unroll
    for (int j = 0; j < 4; ++j)
      bfr[j] = *(const short8*)&smB[cur][(wn + j * 16 + fr) * 32 + fq * 8];
    #pragma unroll
    for (int i = 0; i < 4; ++i)
      #pragma unroll
      for (int j = 0; j < 4; ++j)
        acc[i][j] = __builtin_amdgcn_mfma_f32_16x16x32_bf16(af[i], bfr[j], acc[i][j], 0, 0, 0);
    cur ^= 1;
  }

  const int nE = ne[e];
  float b2v[4];
  #pragma unroll
  for (int j = 0; j < 4; ++j)
    b2v[j] = b2[e * ODIM + nb * 128 + wn + j * 16 + fr];
  #pragma unroll
  for (int i = 0; i < 4; ++i) {
    #pragma unroll
    for (int r = 0; r < 4; ++r) {
      int c = mb * 128 + wm + i * 16 + fq * 4 + r;
      if (c < nE) {
        int s = perm[e * CAP + c];
        float g = gval[s];
        float* orow = out + (size_t)s * ODIM + nb * 128 + wn;
        #pragma unroll
        for (int j = 0; j < 4; ++j)
          orow[j * 16 + fr] = (acc[i][j][r] + b2v[j]) * g;
      }
    }
  }
}

// ------------------------------- launch ---------------------------------------
extern "C" void kernel_launch(void* const* d_in, const int* in_sizes, int n_in,
                              void* d_out, int out_size, void* d_ws, size_t ws_size,
                              hipStream_t stream) {
  const float* feat = (const float*)d_in[0];
  const float* gw   = (const float*)d_in[1];
  const float* w1   = (const float*)d_in[2];
  const float* b1   = (const float*)d_in[3];
  const float* w2   = (const float*)d_in[4];
  const float* b2   = (const float*)d_in[5];
  float* out = (float*)d_out;

  char* ws = (char*)d_ws;
  unsigned short* wt   = (unsigned short*)(ws);                  // 33,554,432 B
  unsigned short* hbuf = (unsigned short*)(ws + 33554432);       // 67,108,864 B
  unsigned short* disp = (unsigned short*)(ws + 100663296);      // 16,777,216 B
  int*   idx  = (int*)  (ws + 117440512);
  float* gval = (float*)(ws + 117473280);
  int*   perm = (int*)  (ws + 117506048);
  float* gsum = (float*)(ws + 117538816);
  int*   ne   = (int*)  (ws + 117538832);

  hipMemsetAsync(d_out, 0, (size_t)S_TOK * ODIM * sizeof(float), stream);
  hipMemsetAsync(ws + 117538816, 0, 32, stream);

  gate_kernel<<<S_TOK / 4, 256, 0, stream>>>(feat, gw, idx, gval, gsum);
  scan_kernel<<<1, 64, 0, stream>>>(idx, perm, ne, gsum, out + (size_t)S_TOK * ODIM);
  transpose_cast<<<dim3(HDIM / 64, MDIM / 64, NEXP), 256, 0, stream>>>(w1, wt, MDIM, HDIM);
  gather_kernel<<<NEXP * CAP, 256, 0, stream>>>(feat, perm, ne, disp);
  fc1_kernel<<<dim3(HDIM / 128, CAP / 128, NEXP), 256, 0, stream>>>(disp, wt, b1, hbuf);
  transpose_cast<<<dim3(ODIM / 64, HDIM / 64, NEXP), 256, 0, stream>>>(w2, wt, HDIM, ODIM);
  fc2_kernel<<<dim3(ODIM / 128, CAP / 128, NEXP), 256, 0, stream>>>(hbuf, wt, b2, perm, ne, gval, out);
}

// Round 3
// 441.125 us; speedup vs baseline: 1.1189x; 1.1189x over previous
//
#include <hip/hip_runtime.h>
#include <stdint.h>

#define S_TOK 8192
#define MDIM  1024
#define HDIM  4096
#define ODIM  1024
#define NEXP  4
#define CAP   2048   // ceil(S/E)

typedef __attribute__((ext_vector_type(8))) short short8;
typedef __attribute__((ext_vector_type(4))) float floatx4;

__device__ __forceinline__ unsigned short f2bf(float x) {
  union { float f; unsigned u; } v; v.f = x;
  unsigned r = v.u + 0x7FFFu + ((v.u >> 16) & 1u);   // RNE
  return (unsigned short)(r >> 16);
}

__device__ __forceinline__ void gl_lds16(const void* g, void* l) {
  __builtin_amdgcn_global_load_lds(
      (const __attribute__((address_space(1))) void*)g,
      (__attribute__((address_space(3))) void*)l, 16, 0, 0);
}

__device__ __forceinline__ float gelu_tanh(float x) {
  // jax.nn.gelu approximate=True
  float z = 0.7978845608028654f * (x + 0.044715f * x * x * x);
  float t = 1.0f - 2.0f / (__expf(2.0f * z) + 1.0f);  // tanh, saturation-safe
  return 0.5f * x * (1.0f + t);
}

// ---------------- gate: logits (fp64 acc), softmax, argmax, gate sums ----------
__global__ __launch_bounds__(256) void gate_kernel(
    const float* __restrict__ feat, const float* __restrict__ gw,
    int* __restrict__ idx, float* __restrict__ gval, float* __restrict__ gsum)
{
  int wave = threadIdx.x >> 6, lane = threadIdx.x & 63;
  int s = blockIdx.x * 4 + wave;
  const float* f = feat + (size_t)s * MDIM;
  double a0 = 0, a1 = 0, a2 = 0, a3 = 0;
  #pragma unroll
  for (int j = 0; j < 16; ++j) {
    int m = lane + j * 64;
    float x = f[m];
    float4 w = ((const float4*)gw)[m];   // gate_w row m: 4 contiguous floats
    a0 += (double)x * w.x; a1 += (double)x * w.y;
    a2 += (double)x * w.z; a3 += (double)x * w.w;
  }
  #pragma unroll
  for (int off = 32; off; off >>= 1) {
    a0 += __shfl_down(a0, off); a1 += __shfl_down(a1, off);
    a2 += __shfl_down(a2, off); a3 += __shfl_down(a3, off);
  }
  __shared__ float bs[4];
  if (threadIdx.x < 4) bs[threadIdx.x] = 0.f;
  __syncthreads();
  if (lane == 0) {
    double lg[4] = {a0, a1, a2, a3};
    double mx = lg[0]; int bi = 0;
    #pragma unroll
    for (int e = 1; e < 4; ++e) if (lg[e] > mx) { mx = lg[e]; bi = e; }  // first-max
    float ex[4]; float den = 0.f;
    #pragma unroll
    for (int e = 0; e < 4; ++e) { ex[e] = __expf((float)(lg[e] - mx)); den += ex[e]; }
    float inv = 1.f / den;
    idx[s]  = bi;
    gval[s] = ex[bi] * inv;
    #pragma unroll
    for (int e = 0; e < 4; ++e) atomicAdd(&bs[e], ex[e] * inv);
  }
  __syncthreads();
  if (threadIdx.x < 4) atomicAdd(&gsum[threadIdx.x], bs[threadIdx.x]);
}

// -------- ordered per-expert rank scan: 16 waves, LDS wave-prefix, l_aux -------
__global__ __launch_bounds__(1024) void scan_kernel(
    const int* __restrict__ idx, int* __restrict__ perm,
    int* __restrict__ ne, const float* __restrict__ gsum,
    float* __restrict__ laux)
{
  const int tid = threadIdx.x, wave = tid >> 6, lane = tid & 63;
  __shared__ int cnt[16][4];
  __shared__ int off[16][4];
  __shared__ int tot[4];
  unsigned long long below = (lane == 0) ? 0ull : ((~0ull) >> (64 - lane));

  int myE[8], loc[8];
  int c[4] = {0, 0, 0, 0};
  #pragma unroll
  for (int j = 0; j < 8; ++j) {
    int s = wave * 512 + j * 64 + lane;
    int ev = idx[s];
    myE[j] = ev;
    #pragma unroll
    for (int e = 0; e < 4; ++e) {
      unsigned long long mb = __ballot(ev == e);
      if (ev == e) loc[j] = c[e] + __popcll(mb & below);
      c[e] += __popcll(mb);   // wave-uniform
    }
  }
  if (lane == 0) {
    #pragma unroll
    for (int e = 0; e < 4; ++e) cnt[wave][e] = c[e];
  }
  __syncthreads();
  if (tid < 64) {            // 16 waves x 4 experts
    int w = tid >> 2, e = tid & 3;
    int o = 0;
    for (int w2 = 0; w2 < 16; ++w2) if (w2 < w) o += cnt[w2][e];
    off[w][e] = o;
    if (w == 15) tot[e] = o + cnt[15][e];
  }
  __syncthreads();
  #pragma unroll
  for (int j = 0; j < 8; ++j) {
    int s = wave * 512 + j * 64 + lane;
    int e = myE[j];
    int rank = off[wave][e] + loc[j];
    if (rank < CAP) perm[e * CAP + rank] = s;   // dropped tokens: no slot
  }
  if (tid < 4) ne[tid] = tot[tid] < CAP ? tot[tid] : CAP;
  if (tid == 0) {   // l_aux: PRE-capacity counts x full softmax means
    float l = 0.f;
    #pragma unroll
    for (int e = 0; e < 4; ++e)
      l += (gsum[e] * (1.0f / S_TOK)) * ((float)tot[e] * (1.0f / S_TOK));
    *laux = l * (float)NEXP;
  }
}

// ---------------- cast + transpose weights: [R,C] f32 -> [C,R] bf16 ------------
__global__ __launch_bounds__(256) void transpose_cast(
    const float* __restrict__ in, unsigned short* __restrict__ out, int R, int Cc)
{
  __shared__ unsigned short tile[64][66];
  in  += (size_t)blockIdx.z * R * Cc;
  out += (size_t)blockIdx.z * R * Cc;
  int c0 = blockIdx.x * 64, r0 = blockIdx.y * 64;
  int tx = threadIdx.x & 15;
  int ty = threadIdx.x >> 4;
  #pragma unroll
  for (int p = 0; p < 4; ++p) {
    int r = ty + p * 16;
    float4 v = *(const float4*)(in + (size_t)(r0 + r) * Cc + c0 + tx * 4);
    tile[r][tx * 4 + 0] = f2bf(v.x);
    tile[r][tx * 4 + 1] = f2bf(v.y);
    tile[r][tx * 4 + 2] = f2bf(v.z);
    tile[r][tx * 4 + 3] = f2bf(v.w);
  }
  __syncthreads();
  #pragma unroll
  for (int p = 0; p < 4; ++p) {
    int c = ty + p * 16;
    ushort4 o;
    o.x = tile[tx * 4 + 0][c];
    o.y = tile[tx * 4 + 1][c];
    o.z = tile[tx * 4 + 2][c];
    o.w = tile[tx * 4 + 3][c];
    *(ushort4*)(out + (size_t)(c0 + c) * R + r0 + tx * 4) = o;
  }
}

// ---------------- gather kept tokens -> bf16 dispatch buffer -------------------
__global__ __launch_bounds__(256) void gather_kernel(
    const float* __restrict__ feat, const int* __restrict__ perm,
    const int* __restrict__ ne, unsigned short* __restrict__ disp)
{
  int b = blockIdx.x;
  int e = b >> 11, c = b & (CAP - 1);
  int m = threadIdx.x * 4;
  ushort4 o;
  if (c < ne[e]) {
    int s = perm[b];
    float4 v = *(const float4*)(feat + (size_t)s * MDIM + m);
    o.x = f2bf(v.x); o.y = f2bf(v.y); o.z = f2bf(v.z); o.w = f2bf(v.w);
  } else {
    o.x = o.y = o.z = o.w = 0;   // empty slot -> zero row (h row = gelu(0)=0)
  }
  *(ushort4*)(disp + (size_t)b * MDIM + m) = o;
}

// ---------------- fc1: disp[E*C,1024] @ w1t[E,4096,1024] -> gelu -> h bf16 -----
// Single-buffer m97 structure (R2's dbuf regressed: barrier vmcnt(0) drains the
// prefetch anyway). 2048 blocks = 8/CU hides the staging latency.
__global__ __launch_bounds__(256) void fc1_kernel(
    const unsigned short* __restrict__ A, const unsigned short* __restrict__ Bt,
    const float* __restrict__ b1, unsigned short* __restrict__ Hb)
{
  const int e = blockIdx.z, nb = blockIdx.x, mb = blockIdx.y;
  const int tid = threadIdx.x, wave = tid >> 6, lane = tid & 63;

  __shared__ __align__(16) unsigned short smA[128 * 32];  // [m][k] 8 KB
  __shared__ __align__(16) unsigned short smB[128 * 32];  // [n][k] 8 KB

  const char* Ag = (const char*)(A + ((size_t)e * CAP + (size_t)mb * 128) * MDIM);
  const char* Bg = (const char*)(Bt + ((size_t)e * HDIM + (size_t)nb * 128) * MDIM);

  int boff0 = (wave * 2 + 0) * 1024 + lane * 16;
  int boff1 = (wave * 2 + 1) * 1024 + lane * 16;
  const char* agp0 = Ag + (size_t)(boff0 >> 6) * 2048 + (boff0 & 63);
  const char* agp1 = Ag + (size_t)(boff1 >> 6) * 2048 + (boff1 & 63);
  const char* bgp0 = Bg + (size_t)(boff0 >> 6) * 2048 + (boff0 & 63);
  const char* bgp1 = Bg + (size_t)(boff1 >> 6) * 2048 + (boff1 & 63);
  unsigned short* sA0 = smA + (wave * 2 + 0) * 512;
  unsigned short* sA1 = smA + (wave * 2 + 1) * 512;
  unsigned short* sB0 = smB + (wave * 2 + 0) * 512;
  unsigned short* sB1 = smB + (wave * 2 + 1) * 512;

  const int wm = (wave & 1) * 64, wn = (wave >> 1) * 64;
  const int fr = lane & 15, fq = lane >> 4;

  floatx4 acc[4][4] = {};

  for (int kt = 0; kt < MDIM / 32; ++kt) {
    int kb = kt * 64;
    gl_lds16(agp0 + kb, sA0);
    gl_lds16(agp1 + kb, sA1);
    gl_lds16(bgp0 + kb, sB0);
    gl_lds16(bgp1 + kb, sB1);
    __syncthreads();
    short8 af[4], bfr[4];
    #pragma unroll
    for (int i = 0; i < 4; ++i)
      af[i] = *(const short8*)&smA[(wm + i * 16 + fr) * 32 + fq * 8];
    #pragma unroll
    for (int j = 0; j < 4; ++j)
      bfr[j] = *(const short8*)&smB[(wn + j * 16 + fr) * 32 + fq * 8];
    #pragma unroll
    for (int i = 0; i < 4; ++i)
      #pragma unroll
      for (int j = 0; j < 4; ++j)
        acc[i][j] = __builtin_amdgcn_mfma_f32_16x16x32_bf16(af[i], bfr[j], acc[i][j], 0, 0, 0);
    __syncthreads();
  }

  unsigned short* Hrow = Hb + (size_t)e * CAP * HDIM;
  #pragma unroll
  for (int j = 0; j < 4; ++j) {
    int gn = nb * 128 + wn + j * 16 + fr;
    float bv = b1[e * HDIM + gn];
    #pragma unroll
    for (int i = 0; i < 4; ++i) {
      int m0 = mb * 128 + wm + i * 16 + fq * 4;
      #pragma unroll
      for (int r = 0; r < 4; ++r)
        Hrow[(size_t)(m0 + r) * HDIM + gn] = f2bf(gelu_tanh(acc[i][j][r] + bv));
    }
  }
}

// ---------------- fc2: h[E*C,4096] @ w2t[E,1024,4096] -> gated scatter ---------
// BM=64 tile -> 1024 blocks = 4 blocks/CU (R1's 512-block grid was the fc2
// latency wall: 2 blocks/CU cannot hide the 900-cyc staging drain).
__global__ __launch_bounds__(256) void fc2_kernel(
    const unsigned short* __restrict__ A, const unsigned short* __restrict__ Bt,
    const float* __restrict__ b2, const int* __restrict__ perm,
    const int* __restrict__ ne, const float* __restrict__ gval,
    float* __restrict__ out)
{
  const int e = blockIdx.z, nb = blockIdx.x, mb = blockIdx.y;  // mb: 0..31
  const int tid = threadIdx.x, wave = tid >> 6, lane = tid & 63;

  __shared__ __align__(16) unsigned short smA[64 * 32];    // [m][k] 4 KB
  __shared__ __align__(16) unsigned short smB[128 * 32];   // [n][k] 8 KB

  const char* Ag = (const char*)(A + ((size_t)e * CAP + (size_t)mb * 64) * HDIM);
  const char* Bg = (const char*)(Bt + ((size_t)e * ODIM + (size_t)nb * 128) * HDIM);

  // A: one 16B DMA per thread covers the 64x32 tile (rows = 64B chunks)
  int boffA = tid * 16;
  const char* agp = Ag + (size_t)(boffA >> 6) * 8192 + (boffA & 63);
  unsigned short* sA = smA + wave * 512;
  // B: two 16B DMAs per thread (rows of h-major w2t are 8192 B)
  int boff0 = (wave * 2 + 0) * 1024 + lane * 16;
  int boff1 = (wave * 2 + 1) * 1024 + lane * 16;
  const char* bgp0 = Bg + (size_t)(boff0 >> 6) * 8192 + (boff0 & 63);
  const char* bgp1 = Bg + (size_t)(boff1 >> 6) * 8192 + (boff1 & 63);
  unsigned short* sB0 = smB + (wave * 2 + 0) * 512;
  unsigned short* sB1 = smB + (wave * 2 + 1) * 512;

  const int wm = (wave & 1) * 32, wn = (wave >> 1) * 64;
  const int fr = lane & 15, fq = lane >> 4;

  floatx4 acc[2][4] = {};

  for (int kt = 0; kt < HDIM / 32; ++kt) {
    int kb = kt * 64;
    gl_lds16(agp + kb, sA);
    gl_lds16(bgp0 + kb, sB0);
    gl_lds16(bgp1 + kb, sB1);
    __syncthreads();
    short8 af[2], bfr[4];
    #pragma unroll
    for (int i = 0; i < 2; ++i)
      af[i] = *(const short8*)&smA[(wm + i * 16 + fr) * 32 + fq * 8];
    #pragma unroll
    for (int j = 0; j < 4; ++j)
      bfr[j] = *(const short8*)&smB[(wn + j * 16 + fr) * 32 + fq * 8];
    #pragma unroll
    for (int i = 0; i < 2; ++i)
      #pragma unroll
      for (int j = 0; j < 4; ++j)
        acc[i][j] = __builtin_amdgcn_mfma_f32_16x16x32_bf16(af[i], bfr[j], acc[i][j], 0, 0, 0);
    __syncthreads();
  }

  const int nE = ne[e];
  float b2v[4];
  #pragma unroll
  for (int j = 0; j < 4; ++j)
    b2v[j] = b2[e * ODIM + nb * 128 + wn + j * 16 + fr];
  #pragma unroll
  for (int i = 0; i < 2; ++i) {
    #pragma unroll
    for (int r = 0; r < 4; ++r) {
      int c = mb * 64 + wm + i * 16 + fq * 4 + r;
      if (c < nE) {
        int s = perm[e * CAP + c];
        float g = gval[s];
        float* orow = out + (size_t)s * ODIM + nb * 128 + wn;
        #pragma unroll
        for (int j = 0; j < 4; ++j)
          orow[j * 16 + fr] = (acc[i][j][r] + b2v[j]) * g;
      }
    }
  }
}

// ------------------------------- launch ---------------------------------------
extern "C" void kernel_launch(void* const* d_in, const int* in_sizes, int n_in,
                              void* d_out, int out_size, void* d_ws, size_t ws_size,
                              hipStream_t stream) {
  const float* feat = (const float*)d_in[0];
  const float* gw   = (const float*)d_in[1];
  const float* w1   = (const float*)d_in[2];
  const float* b1   = (const float*)d_in[3];
  const float* w2   = (const float*)d_in[4];
  const float* b2   = (const float*)d_in[5];
  float* out = (float*)d_out;

  char* ws = (char*)d_ws;
  unsigned short* wt   = (unsigned short*)(ws);                  // 33,554,432 B
  unsigned short* hbuf = (unsigned short*)(ws + 33554432);       // 67,108,864 B
  unsigned short* disp = (unsigned short*)(ws + 100663296);      // 16,777,216 B
  int*   idx  = (int*)  (ws + 117440512);
  float* gval = (float*)(ws + 117473280);
  int*   perm = (int*)  (ws + 117506048);
  float* gsum = (float*)(ws + 117538816);
  int*   ne   = (int*)  (ws + 117538832);

  hipMemsetAsync(d_out, 0, (size_t)S_TOK * ODIM * sizeof(float), stream);
  hipMemsetAsync(ws + 117538816, 0, 32, stream);

  gate_kernel<<<S_TOK / 4, 256, 0, stream>>>(feat, gw, idx, gval, gsum);
  scan_kernel<<<1, 1024, 0, stream>>>(idx, perm, ne, gsum, out + (size_t)S_TOK * ODIM);
  transpose_cast<<<dim3(HDIM / 64, MDIM / 64, NEXP), 256, 0, stream>>>(w1, wt, MDIM, HDIM);
  gather_kernel<<<NEXP * CAP, 256, 0, stream>>>(feat, perm, ne, disp);
  fc1_kernel<<<dim3(HDIM / 128, CAP / 128, NEXP), 256, 0, stream>>>(disp, wt, b1, hbuf);
  transpose_cast<<<dim3(ODIM / 64, HDIM / 64, NEXP), 256, 0, stream>>>(w2, wt, HDIM, ODIM);
  fc2_kernel<<<dim3(ODIM / 128, CAP / 64, NEXP), 256, 0, stream>>>(hbuf, wt, b2, perm, ne, gval, out);
}